// Round 11
// baseline (12075.720 us; speedup 1.0000x reference)
//
#include <hip/hip_runtime.h>
#include <hip/hip_bf16.h>
#include <hip/hip_fp16.h>

#define VOCABN 50257
#define EMBEDN 256
#define HIDDENN 256
#define TAGSN 8192
#define SEQN 8192

typedef int i32x4 __attribute__((ext_vector_type(4)));

__device__ __forceinline__ float sigm(float x) {
    x = fminf(fmaxf(x, -30.f), 30.f);
    return 1.f / (1.f + __expf(-x));
}

__device__ __forceinline__ float tanh_f(float x) {
    x = fminf(fmaxf(x, -15.f), 15.f);
    float e = __expf(-2.f * x);
    return (1.f - e) / (1.f + e);
}

__device__ __forceinline__ i32x4 mfma_i8(i32x4 a, i32x4 b, i32x4 c) {
#if __has_builtin(__builtin_amdgcn_mfma_i32_16x16x64_i8)
    return __builtin_amdgcn_mfma_i32_16x16x64_i8(a, b, c, 0, 0, 0);
#else
    i32x4 d = c;
    asm("v_mfma_i32_16x16x64_i8 %0, %1, %2, %0" : "+v"(d) : "v"(a), "v"(b));
    return d;
#endif
}

// ---------------------------------------------------------------------------
// prep: WxT[k][o] = W_gate(o)[o&255][k]; bcat[o] = b_gate(o)[o&255]
// ---------------------------------------------------------------------------
__global__ __launch_bounds__(256) void prep_kernel(
    const float* __restrict__ Wf, const float* __restrict__ Wi,
    const float* __restrict__ Wg, const float* __restrict__ Wo,
    const float* __restrict__ bf, const float* __restrict__ bi,
    const float* __restrict__ bg, const float* __restrict__ bo,
    float* __restrict__ WxT, float* __restrict__ bcat)
{
    int idx = blockIdx.x * 256 + threadIdx.x;   // 0..262143
    int k = idx >> 10, o = idx & 1023;
    int g = o >> 8, r = o & 255;
    const float* W = (g == 0) ? Wf : (g == 1) ? Wi : (g == 2) ? Wg : Wo;
    WxT[idx] = W[r * 512 + k];
    if (idx < 1024) {
        const float* b = (g == 0) ? bf : (g == 1) ? bi : (g == 2) ? bg : bo;
        bcat[idx] = b[r];
    }
}

// ---------------------------------------------------------------------------
// xproj[s][o] = sum_k emb[sentence[s]][k] * WxT[k][o] + bcat[o]
// ---------------------------------------------------------------------------
__global__ __launch_bounds__(256) void xproj_kernel(
    const int* __restrict__ sentence, const float* __restrict__ emb,
    const float* __restrict__ WxT, const float* __restrict__ bcat,
    float* __restrict__ xproj)
{
    __shared__ __align__(16) float At[32 * 256];
    const int tid = threadIdx.x;
    const int s0 = blockIdx.y * 32;
    const int o = blockIdx.x * 256 + tid;

#pragma unroll
    for (int i = 0; i < 32; i++) {
        int idx = tid + i * 256;
        int srow = idx >> 8, c = idx & 255;
        At[idx] = emb[(size_t)sentence[s0 + srow] * 256 + c];
    }
    __syncthreads();

    float acc[32];
    float b = bcat[o];
#pragma unroll
    for (int i = 0; i < 32; i++) acc[i] = b;

    for (int k4 = 0; k4 < 64; k4++) {
        float4 w;
        w.x = WxT[(k4 * 4 + 0) * 1024 + o];
        w.y = WxT[(k4 * 4 + 1) * 1024 + o];
        w.z = WxT[(k4 * 4 + 2) * 1024 + o];
        w.w = WxT[(k4 * 4 + 3) * 1024 + o];
#pragma unroll
        for (int i = 0; i < 32; i++) {
            float4 a = *(const float4*)&At[i * 256 + k4 * 4];
            acc[i] += a.x * w.x + a.y * w.y + a.z * w.z + a.w * w.w;
        }
    }
#pragma unroll
    for (int i = 0; i < 32; i++)
        xproj[(size_t)(s0 + i) * 1024 + o] = acc[i];
}

// ---------------------------------------------------------------------------
// Persistent single-workgroup LSTM via int8 MFMA (16x16x64 i8, i32 accum).
// r11: 1024 threads = 16 waves (4 waves/SIMD for latency hiding). Wave wq
// owns units [16wq,16wq+16) x 4 gates = 4 tiles (one tile per gate).
// Per-wave registers: 16 weight frags (64 regs) + acc 16 + working ~40
// <= 128-reg budget at 4 waves/EU -> no spill.
// Epilogue needs NO cross-lane exchange: after the j=row16&3 reg-select,
// lane (kg,row16) holds f,i,g,o preacts of the SAME unit u=16wq+4kg+j.
// Each unit's activation chain is computed 4x redundantly (row16>>2 copies,
// deterministic identical); lanes with (l&12)==0 write h. Zero bpermutes.
// Weights per-row symmetric i8 (scale=rowmax/127), h quantized i8 per step,
// exact i32 accumulation, dequant pre = acc*rowmax/127^2 + xp (verified r10).
// ---------------------------------------------------------------------------
__global__ __launch_bounds__(1024, 4) void lstm_kernel(
    const float* __restrict__ Wf, const float* __restrict__ Wi,
    const float* __restrict__ Wg, const float* __restrict__ Wo,
    const float* __restrict__ xproj, float* __restrict__ h_all)
{
    __shared__ __align__(16) char hb8[2][256];   // dbuf h (i8)
    __shared__ float scLds[4][256];              // rowmax per (gate, unit)

    const int t = threadIdx.x;
    const int wq = t >> 6;         // wave 0..15
    const int l = t & 63;          // lane
    const int row16 = l & 15;      // A row (D col replicated)
    const int kg = l >> 4;         // k-group 0..3 (16 bytes each within K=64)

    // ---- one-time setup: per-row maxabs + quantize into 16 i8 frags ----
    i32x4 Areg[16];                // [gate g][kt] = Areg[g*4+kt]
#pragma unroll
    for (int g = 0; g < 4; g++) {
        const float* W = (g == 0) ? Wf : (g == 1) ? Wi : (g == 2) ? Wg : Wo;
        const int row = 16 * wq + row16;
        const float* base = W + row * 512 + 256;   // h-part of the row

        // pass 1: maxabs over this lane's 64 elems (k = kt*64 + kg*16 + j)
        float mx = 0.f;
#pragma unroll
        for (int kt = 0; kt < 4; kt++)
#pragma unroll
            for (int q = 0; q < 4; q++) {
                float4 v4 = *(const float4*)&base[kt * 64 + kg * 16 + 4 * q];
                mx = fmaxf(mx, fmaxf(fmaxf(fabsf(v4.x), fabsf(v4.y)),
                                     fmaxf(fabsf(v4.z), fabsf(v4.w))));
            }
        // combine across the 4 kg lanes (same row16)
        mx = fmaxf(mx, __shfl_xor(mx, 16, 64));
        mx = fmaxf(mx, __shfl_xor(mx, 32, 64));
        mx = fmaxf(mx, 1e-20f);
        const float inv = 127.f / mx;

        // pass 2: quantize & pack (linear k order; A/B share it -> exact dot)
#pragma unroll
        for (int kt = 0; kt < 4; kt++) {
            unsigned int r[4];
#pragma unroll
            for (int q = 0; q < 4; q++) {
                float4 v4 = *(const float4*)&base[kt * 64 + kg * 16 + 4 * q];
                unsigned int b0 = (unsigned int)(__float2int_rn(v4.x * inv) & 255);
                unsigned int b1 = (unsigned int)(__float2int_rn(v4.y * inv) & 255);
                unsigned int b2 = (unsigned int)(__float2int_rn(v4.z * inv) & 255);
                unsigned int b3 = (unsigned int)(__float2int_rn(v4.w * inv) & 255);
                r[q] = b0 | (b1 << 8) | (b2 << 16) | (b3 << 24);
            }
            Areg[g * 4 + kt] = i32x4{(int)r[0], (int)r[1], (int)r[2], (int)r[3]};
        }
        if (kg == 0) scLds[g][row] = mx;           // publish rowmax
    }
    if (t < 256) { hb8[0][t] = 0; hb8[1][t] = 0; }

    // this lane's owned unit (4x redundant across row16>>2)
    const int u = 16 * wq + 4 * kg + (row16 & 3);
    const bool selA = (row16 & 1) != 0, selB = (row16 & 2) != 0;
    const bool writer = (row16 & 12) == 0;
    float cst = 0.f;

    __syncthreads();

    // per-lane dequant scales (rowmax / 127^2) for the 4 gates of unit u
    const float qs = 1.f / (127.f * 127.f);
    float scl[4];
#pragma unroll
    for (int g = 0; g < 4; g++) scl[g] = scLds[g][u] * qs;

    int buf = 0;
    for (int s = 0; s < SEQN; ++s) {
        // xp for the tail (global scalar loads; MFMA phase hides them)
        const float* xr = xproj + (size_t)s * 1024;
        float xp0 = xr[u];
        float xp1 = xr[256 + u];
        float xp2 = xr[512 + u];
        float xp3 = xr[768 + u];

        const char* hb = hb8[buf];
        i32x4 acc[4];
        const i32x4 z = {0, 0, 0, 0};

        // kt0 (C = shared zero)
        {
            i32x4 b = *(const i32x4*)&hb[0 * 64 + kg * 16];
#pragma unroll
            for (int g = 0; g < 4; g++)
                acc[g] = mfma_i8(Areg[g * 4 + 0], b, z);
        }
#pragma unroll
        for (int kt = 1; kt < 4; kt++) {
            i32x4 b = *(const i32x4*)&hb[kt * 64 + kg * 16];
#pragma unroll
            for (int g = 0; g < 4; g++)
                acc[g] = mfma_i8(Areg[g * 4 + kt], b, acc[g]);
        }

        // ---- in-lane epilogue (no cross-lane exchange) ----
        // reg-select j = row16&3 -> preact(gate g, unit u) in this lane
        float pre[4];
#pragma unroll
        for (int g = 0; g < 4; g++) {
            int t01 = selA ? acc[g][1] : acc[g][0];
            int t23 = selA ? acc[g][3] : acc[g][2];
            pre[g] = (float)(selB ? t23 : t01) * scl[g];
        }
        float fg = sigm(pre[0] + xp0);
        float ig = sigm(pre[1] + xp1);
        float gg = tanh_f(pre[2] + xp2);
        float og = sigm(pre[3] + xp3);
        cst = fg * cst + ig * gg;
        float h = og * tanh_f(cst);
        if (writer) {
            h_all[s * 256 + u] = h;
            hb8[buf ^ 1][u] = (char)__float2int_rn(h * 127.f);
        }
        __syncthreads();   // new h visible for next step
        buf ^= 1;
    }
}

// ---------------------------------------------------------------------------
// logits[t][v] = h_all[t] . Wtag[v] + btag[v]   (64x64 tile / block, 4x4 micro)
// ---------------------------------------------------------------------------
__global__ __launch_bounds__(256) void logits_kernel(
    const float* __restrict__ h_all, const float* __restrict__ Wtag,
    const float* __restrict__ btag, float* __restrict__ out)
{
    __shared__ __align__(16) float At[64 * 68];
    __shared__ __align__(16) float Bt[64 * 68];
    const int tid = threadIdx.x;
    const int tx = tid & 15, ty = tid >> 4;
    const int t0 = blockIdx.y * 64, v0 = blockIdx.x * 64;
    float acc[4][4] = {};

    for (int kc = 0; kc < 256; kc += 64) {
        __syncthreads();
#pragma unroll
        for (int i = 0; i < 16; i++) {
            int idx = tid + i * 256;
            int rrow = idx >> 6, ccol = idx & 63;
            At[rrow * 68 + ccol] = h_all[(t0 + rrow) * 256 + kc + ccol];
            Bt[rrow * 68 + ccol] = Wtag[(size_t)(v0 + rrow) * 256 + kc + ccol];
        }
        __syncthreads();
#pragma unroll
        for (int k4 = 0; k4 < 16; k4++) {
            float4 av[4], bv[4];
#pragma unroll
            for (int i = 0; i < 4; i++) av[i] = *(const float4*)&At[(ty + 16 * i) * 68 + k4 * 4];
#pragma unroll
            for (int j = 0; j < 4; j++) bv[j] = *(const float4*)&Bt[(tx + 16 * j) * 68 + k4 * 4];
#pragma unroll
            for (int i = 0; i < 4; i++)
#pragma unroll
                for (int j = 0; j < 4; j++)
                    acc[i][j] += av[i].x * bv[j].x + av[i].y * bv[j].y +
                                 av[i].z * bv[j].z + av[i].w * bv[j].w;
        }
    }
#pragma unroll
    for (int j = 0; j < 4; j++) {
        float bb = btag[v0 + tx + 16 * j];
#pragma unroll
        for (int i = 0; i < 4; i++) {
            out[(size_t)(t0 + ty + 16 * i) * TAGSN + v0 + tx + 16 * j] = acc[i][j] + bb;
        }
    }
}

// ---------------------------------------------------------------------------
// in-place row-wise log_softmax over 8192 columns (one block per row)
// ---------------------------------------------------------------------------
__global__ __launch_bounds__(256) void lsm_kernel(float* __restrict__ out)
{
    const int row = blockIdx.x, tid = threadIdx.x;
    float* p = out + (size_t)row * TAGSN;
    float v[32];
#pragma unroll
    for (int j = 0; j < 32; j++) v[j] = p[tid + 256 * j];

    float m = -1e30f;
#pragma unroll
    for (int j = 0; j < 32; j++) m = fmaxf(m, v[j]);
#pragma unroll
    for (int off = 32; off; off >>= 1) m = fmaxf(m, __shfl_xor(m, off, 64));
    __shared__ float red[4];
    if ((tid & 63) == 0) red[tid >> 6] = m;
    __syncthreads();
    m = fmaxf(fmaxf(red[0], red[1]), fmaxf(red[2], red[3]));

    float s = 0.f;
#pragma unroll
    for (int j = 0; j < 32; j++) s += __expf(v[j] - m);
#pragma unroll
    for (int off = 32; off; off >>= 1) s += __shfl_xor(s, off, 64);
    __shared__ float red2[4];
    if ((tid & 63) == 0) red2[tid >> 6] = s;
    __syncthreads();
    s = (red2[0] + red2[1]) + (red2[2] + red2[3]);

    float lse = m + __logf(s);
#pragma unroll
    for (int j = 0; j < 32; j++) p[tid + 256 * j] = v[j] - lse;
}

// ---------------------------------------------------------------------------
extern "C" void kernel_launch(void* const* d_in, const int* in_sizes, int n_in,
                              void* d_out, int out_size, void* d_ws, size_t ws_size,
                              hipStream_t stream)
{
    const int*   sentence = (const int*)d_in[0];
    const float* emb  = (const float*)d_in[1];
    const float* Wf   = (const float*)d_in[2];
    const float* bf   = (const float*)d_in[3];
    const float* Wi   = (const float*)d_in[4];
    const float* bi   = (const float*)d_in[5];
    const float* Wg   = (const float*)d_in[6];
    const float* bg   = (const float*)d_in[7];
    const float* Wo   = (const float*)d_in[8];
    const float* bo   = (const float*)d_in[9];
    const float* Wtag = (const float*)d_in[10];
    const float* btag = (const float*)d_in[11];
    float* out = (float*)d_out;

    char* ws = (char*)d_ws;
    float* WxT   = (float*)(ws);                                      // 1 MiB
    float* bcat  = (float*)(ws + (1u << 20));                         // 4 KiB
    float* xproj = (float*)(ws + (1u << 20) + (1u << 16));            // 32 MiB
    float* h_all = (float*)(ws + (1u << 20) + (1u << 16) + (32u << 20)); // 8 MiB

    prep_kernel<<<1024, 256, 0, stream>>>(Wf, Wi, Wg, Wo, bf, bi, bg, bo, WxT, bcat);
    xproj_kernel<<<dim3(4, 256), 256, 0, stream>>>(sentence, emb, WxT, bcat, xproj);
    lstm_kernel<<<1, 1024, 0, stream>>>(Wf, Wi, Wg, Wo, xproj, h_all);
    logits_kernel<<<dim3(128, 128), 256, 0, stream>>>(h_all, Wtag, btag, out);
    lsm_kernel<<<8192, 256, 0, stream>>>(out);
}

// Round 12
// 11790.382 us; speedup vs baseline: 1.0242x; 1.0242x over previous
//
#include <hip/hip_runtime.h>
#include <hip/hip_bf16.h>
#include <hip/hip_fp16.h>

#define VOCABN 50257
#define EMBEDN 256
#define HIDDENN 256
#define TAGSN 8192
#define SEQN 8192

typedef int i32x4 __attribute__((ext_vector_type(4)));

// clamp-free, NaN-safe (denominator >= 1 always; inf -> correct limit)
__device__ __forceinline__ float sigm(float x) {
    return 1.f / (1.f + __expf(-x));
}
__device__ __forceinline__ float tanh_f(float x) {
    return 2.f / (1.f + __expf(-2.f * x)) - 1.f;
}

__device__ __forceinline__ i32x4 mfma_i8(i32x4 a, i32x4 b, i32x4 c) {
#if __has_builtin(__builtin_amdgcn_mfma_i32_16x16x64_i8)
    return __builtin_amdgcn_mfma_i32_16x16x64_i8(a, b, c, 0, 0, 0);
#else
    i32x4 d = c;
    asm("v_mfma_i32_16x16x64_i8 %0, %1, %2, %0" : "+v"(d) : "v"(a), "v"(b));
    return d;
#endif
}

// ---------------------------------------------------------------------------
// prep: WxT[k][o] = W_gate(o)[o&255][k]; bcat[o] = b_gate(o)[o&255]
// ---------------------------------------------------------------------------
__global__ __launch_bounds__(256) void prep_kernel(
    const float* __restrict__ Wf, const float* __restrict__ Wi,
    const float* __restrict__ Wg, const float* __restrict__ Wo,
    const float* __restrict__ bf, const float* __restrict__ bi,
    const float* __restrict__ bg, const float* __restrict__ bo,
    float* __restrict__ WxT, float* __restrict__ bcat)
{
    int idx = blockIdx.x * 256 + threadIdx.x;   // 0..262143
    int k = idx >> 10, o = idx & 1023;
    int g = o >> 8, r = o & 255;
    const float* W = (g == 0) ? Wf : (g == 1) ? Wi : (g == 2) ? Wg : Wo;
    WxT[idx] = W[r * 512 + k];
    if (idx < 1024) {
        const float* b = (g == 0) ? bf : (g == 1) ? bi : (g == 2) ? bg : bo;
        bcat[idx] = b[r];
    }
}

// ---------------------------------------------------------------------------
// xproj[s][o] = sum_k emb[sentence[s]][k] * WxT[k][o] + bcat[o]
// ---------------------------------------------------------------------------
__global__ __launch_bounds__(256) void xproj_kernel(
    const int* __restrict__ sentence, const float* __restrict__ emb,
    const float* __restrict__ WxT, const float* __restrict__ bcat,
    float* __restrict__ xproj)
{
    __shared__ __align__(16) float At[32 * 256];
    const int tid = threadIdx.x;
    const int s0 = blockIdx.y * 32;
    const int o = blockIdx.x * 256 + tid;

#pragma unroll
    for (int i = 0; i < 32; i++) {
        int idx = tid + i * 256;
        int srow = idx >> 8, c = idx & 255;
        At[idx] = emb[(size_t)sentence[s0 + srow] * 256 + c];
    }
    __syncthreads();

    float acc[32];
    float b = bcat[o];
#pragma unroll
    for (int i = 0; i < 32; i++) acc[i] = b;

    for (int k4 = 0; k4 < 64; k4++) {
        float4 w;
        w.x = WxT[(k4 * 4 + 0) * 1024 + o];
        w.y = WxT[(k4 * 4 + 1) * 1024 + o];
        w.z = WxT[(k4 * 4 + 2) * 1024 + o];
        w.w = WxT[(k4 * 4 + 3) * 1024 + o];
#pragma unroll
        for (int i = 0; i < 32; i++) {
            float4 a = *(const float4*)&At[i * 256 + k4 * 4];
            acc[i] += a.x * w.x + a.y * w.y + a.z * w.z + a.w * w.w;
        }
    }
#pragma unroll
    for (int i = 0; i < 32; i++)
        xproj[(size_t)(s0 + i) * 1024 + o] = acc[i];
}

// ---------------------------------------------------------------------------
// Persistent single-workgroup LSTM via int8 MFMA (16x16x64 i8, i32 accum).
// r12: 1024 threads = 16 waves, amdgpu_waves_per_eu(4,4) pins the register
// budget to 128/wave so everything stays in arch VGPRs (r11 failure: the
// allocator targeted 8 waves/EU -> 64 VGPR -> AGPR shuffling, VALUBusy x1.5).
// Wave wq owns units [16wq,16wq+16) x 4 gates = 4 tiles (one per gate);
// weights = 16 i8 frags = 64 VGPRs. In-lane epilogue, no cross-lane ops.
// h_all global writes are staged in LDS (hstage[64][256]) and dumped every
// 64 steps: the per-step __syncthreads then has NO outstanding VMEM to
// drain (r11: it waited on the h_all store ack every step, ~200 serial cy).
// ---------------------------------------------------------------------------
__global__ __launch_bounds__(1024)
__attribute__((amdgpu_waves_per_eu(4, 4)))
void lstm_kernel(
    const float* __restrict__ Wf, const float* __restrict__ Wi,
    const float* __restrict__ Wg, const float* __restrict__ Wo,
    const float* __restrict__ xproj, float* __restrict__ h_all)
{
    __shared__ __align__(16) char hb8[2][256];   // dbuf h (i8)
    __shared__ float scLds[4][256];              // rowmax per (gate, unit)
    __shared__ __align__(16) float hstage[64 * 256];  // 64 KiB h staging

    const int t = threadIdx.x;
    const int wq = t >> 6;         // wave 0..15
    const int l = t & 63;          // lane
    const int row16 = l & 15;      // A row (D col replicated)
    const int kg = l >> 4;         // k-group 0..3 (16 bytes each within K=64)

    // ---- one-time setup: per-row maxabs + quantize into 16 i8 frags ----
    i32x4 Areg[16];                // [gate g][kt] = Areg[g*4+kt]
#pragma unroll
    for (int g = 0; g < 4; g++) {
        const float* W = (g == 0) ? Wf : (g == 1) ? Wi : (g == 2) ? Wg : Wo;
        const int row = 16 * wq + row16;
        const float* base = W + row * 512 + 256;   // h-part of the row

        // pass 1: maxabs over this lane's 64 elems (k = kt*64 + kg*16 + j)
        float mx = 0.f;
#pragma unroll
        for (int kt = 0; kt < 4; kt++)
#pragma unroll
            for (int q = 0; q < 4; q++) {
                float4 v4 = *(const float4*)&base[kt * 64 + kg * 16 + 4 * q];
                mx = fmaxf(mx, fmaxf(fmaxf(fabsf(v4.x), fabsf(v4.y)),
                                     fmaxf(fabsf(v4.z), fabsf(v4.w))));
            }
        // combine across the 4 kg lanes (same row16)
        mx = fmaxf(mx, __shfl_xor(mx, 16, 64));
        mx = fmaxf(mx, __shfl_xor(mx, 32, 64));
        mx = fmaxf(mx, 1e-20f);
        const float inv = 127.f / mx;

        // pass 2: quantize & pack (linear k order; A/B share it -> exact dot)
#pragma unroll
        for (int kt = 0; kt < 4; kt++) {
            unsigned int r[4];
#pragma unroll
            for (int q = 0; q < 4; q++) {
                float4 v4 = *(const float4*)&base[kt * 64 + kg * 16 + 4 * q];
                unsigned int b0 = (unsigned int)(__float2int_rn(v4.x * inv) & 255);
                unsigned int b1 = (unsigned int)(__float2int_rn(v4.y * inv) & 255);
                unsigned int b2 = (unsigned int)(__float2int_rn(v4.z * inv) & 255);
                unsigned int b3 = (unsigned int)(__float2int_rn(v4.w * inv) & 255);
                r[q] = b0 | (b1 << 8) | (b2 << 16) | (b3 << 24);
            }
            Areg[g * 4 + kt] = i32x4{(int)r[0], (int)r[1], (int)r[2], (int)r[3]};
        }
        if (kg == 0) scLds[g][row] = mx;           // publish rowmax
    }
    if (t < 256) { hb8[0][t] = 0; hb8[1][t] = 0; }

    // this lane's owned unit (4x redundant across row16>>2)
    const int u = 16 * wq + 4 * kg + (row16 & 3);
    const bool selA = (row16 & 1) != 0, selB = (row16 & 2) != 0;
    const bool writer = (row16 & 12) == 0;
    float cst = 0.f;

    __syncthreads();

    // per-lane dequant scales (rowmax / 127^2) for the 4 gates of unit u
    const float qs = 1.f / (127.f * 127.f);
    float scl[4];
#pragma unroll
    for (int g = 0; g < 4; g++) scl[g] = scLds[g][u] * qs;

    int buf = 0;
    for (int s = 0; s < SEQN; ++s) {
        // xp for the tail (global scalar loads; MFMA phase hides them)
        const float* xr = xproj + (size_t)s * 1024;
        float xp0 = xr[u];
        float xp1 = xr[256 + u];
        float xp2 = xr[512 + u];
        float xp3 = xr[768 + u];

        const char* hb = hb8[buf];
        i32x4 acc[4];
        const i32x4 z = {0, 0, 0, 0};

        // kt0 (C = shared zero)
        {
            i32x4 b = *(const i32x4*)&hb[0 * 64 + kg * 16];
#pragma unroll
            for (int g = 0; g < 4; g++)
                acc[g] = mfma_i8(Areg[g * 4 + 0], b, z);
        }
#pragma unroll
        for (int kt = 1; kt < 4; kt++) {
            i32x4 b = *(const i32x4*)&hb[kt * 64 + kg * 16];
#pragma unroll
            for (int g = 0; g < 4; g++)
                acc[g] = mfma_i8(Areg[g * 4 + kt], b, acc[g]);
        }

        // ---- in-lane epilogue (no cross-lane exchange) ----
        // reg-select j = row16&3 -> preact(gate g, unit u) in this lane
        float pre[4];
#pragma unroll
        for (int g = 0; g < 4; g++) {
            int t01 = selA ? acc[g][1] : acc[g][0];
            int t23 = selA ? acc[g][3] : acc[g][2];
            pre[g] = (float)(selB ? t23 : t01) * scl[g];
        }
        float fg = sigm(pre[0] + xp0);
        float ig = sigm(pre[1] + xp1);
        float gg = tanh_f(pre[2] + xp2);
        float og = sigm(pre[3] + xp3);
        cst = fg * cst + ig * gg;
        float h = og * tanh_f(cst);
        if (writer) {
            hstage[(s & 63) * 256 + u] = h;        // LDS, not global
            hb8[buf ^ 1][u] = (char)__float2int_rn(h * 127.f);
        }
        // every 64 steps: dump staged h to global (amortizes the VMEM drain)
        if ((s & 63) == 63) {
            __syncthreads();                       // hstage complete
            float* dst = h_all + (size_t)(s - 63) * 256;
#pragma unroll
            for (int i = 0; i < 16; i++)
                dst[i * 1024 + t] = hstage[i * 1024 + t];
        }
        __syncthreads();   // new h visible; no outstanding VMEM on fast path
        buf ^= 1;
    }
}

// ---------------------------------------------------------------------------
// logits[t][v] = h_all[t] . Wtag[v] + btag[v]   (64x64 tile / block, 4x4 micro)
// ---------------------------------------------------------------------------
__global__ __launch_bounds__(256) void logits_kernel(
    const float* __restrict__ h_all, const float* __restrict__ Wtag,
    const float* __restrict__ btag, float* __restrict__ out)
{
    __shared__ __align__(16) float At[64 * 68];
    __shared__ __align__(16) float Bt[64 * 68];
    const int tid = threadIdx.x;
    const int tx = tid & 15, ty = tid >> 4;
    const int t0 = blockIdx.y * 64, v0 = blockIdx.x * 64;
    float acc[4][4] = {};

    for (int kc = 0; kc < 256; kc += 64) {
        __syncthreads();
#pragma unroll
        for (int i = 0; i < 16; i++) {
            int idx = tid + i * 256;
            int rrow = idx >> 6, ccol = idx & 63;
            At[rrow * 68 + ccol] = h_all[(t0 + rrow) * 256 + kc + ccol];
            Bt[rrow * 68 + ccol] = Wtag[(size_t)(v0 + rrow) * 256 + kc + ccol];
        }
        __syncthreads();
#pragma unroll
        for (int k4 = 0; k4 < 16; k4++) {
            float4 av[4], bv[4];
#pragma unroll
            for (int i = 0; i < 4; i++) av[i] = *(const float4*)&At[(ty + 16 * i) * 68 + k4 * 4];
#pragma unroll
            for (int j = 0; j < 4; j++) bv[j] = *(const float4*)&Bt[(tx + 16 * j) * 68 + k4 * 4];
#pragma unroll
            for (int i = 0; i < 4; i++)
#pragma unroll
                for (int j = 0; j < 4; j++)
                    acc[i][j] += av[i].x * bv[j].x + av[i].y * bv[j].y +
                                 av[i].z * bv[j].z + av[i].w * bv[j].w;
        }
    }
#pragma unroll
    for (int j = 0; j < 4; j++) {
        float bb = btag[v0 + tx + 16 * j];
#pragma unroll
        for (int i = 0; i < 4; i++) {
            out[(size_t)(t0 + ty + 16 * i) * TAGSN + v0 + tx + 16 * j] = acc[i][j] + bb;
        }
    }
}

// ---------------------------------------------------------------------------
// in-place row-wise log_softmax over 8192 columns (one block per row)
// ---------------------------------------------------------------------------
__global__ __launch_bounds__(256) void lsm_kernel(float* __restrict__ out)
{
    const int row = blockIdx.x, tid = threadIdx.x;
    float* p = out + (size_t)row * TAGSN;
    float v[32];
#pragma unroll
    for (int j = 0; j < 32; j++) v[j] = p[tid + 256 * j];

    float m = -1e30f;
#pragma unroll
    for (int j = 0; j < 32; j++) m = fmaxf(m, v[j]);
#pragma unroll
    for (int off = 32; off; off >>= 1) m = fmaxf(m, __shfl_xor(m, off, 64));
    __shared__ float red[4];
    if ((tid & 63) == 0) red[tid >> 6] = m;
    __syncthreads();
    m = fmaxf(fmaxf(red[0], red[1]), fmaxf(red[2], red[3]));

    float s = 0.f;
#pragma unroll
    for (int j = 0; j < 32; j++) s += __expf(v[j] - m);
#pragma unroll
    for (int off = 32; off; off >>= 1) s += __shfl_xor(s, off, 64);
    __shared__ float red2[4];
    if ((tid & 63) == 0) red2[tid >> 6] = s;
    __syncthreads();
    s = (red2[0] + red2[1]) + (red2[2] + red2[3]);

    float lse = m + __logf(s);
#pragma unroll
    for (int j = 0; j < 32; j++) p[tid + 256 * j] = v[j] - lse;
}

// ---------------------------------------------------------------------------
extern "C" void kernel_launch(void* const* d_in, const int* in_sizes, int n_in,
                              void* d_out, int out_size, void* d_ws, size_t ws_size,
                              hipStream_t stream)
{
    const int*   sentence = (const int*)d_in[0];
    const float* emb  = (const float*)d_in[1];
    const float* Wf   = (const float*)d_in[2];
    const float* bf   = (const float*)d_in[3];
    const float* Wi   = (const float*)d_in[4];
    const float* bi   = (const float*)d_in[5];
    const float* Wg   = (const float*)d_in[6];
    const float* bg   = (const float*)d_in[7];
    const float* Wo   = (const float*)d_in[8];
    const float* bo   = (const float*)d_in[9];
    const float* Wtag = (const float*)d_in[10];
    const float* btag = (const float*)d_in[11];
    float* out = (float*)d_out;

    char* ws = (char*)d_ws;
    float* WxT   = (float*)(ws);                                      // 1 MiB
    float* bcat  = (float*)(ws + (1u << 20));                         // 4 KiB
    float* xproj = (float*)(ws + (1u << 20) + (1u << 16));            // 32 MiB
    float* h_all = (float*)(ws + (1u << 20) + (1u << 16) + (32u << 20)); // 8 MiB

    prep_kernel<<<1024, 256, 0, stream>>>(Wf, Wi, Wg, Wo, bf, bi, bg, bo, WxT, bcat);
    xproj_kernel<<<dim3(4, 256), 256, 0, stream>>>(sentence, emb, WxT, bcat, xproj);
    lstm_kernel<<<1, 1024, 0, stream>>>(Wf, Wi, Wg, Wo, xproj, h_all);
    logits_kernel<<<dim3(128, 128), 256, 0, stream>>>(h_all, Wtag, btag, out);
    lsm_kernel<<<8192, 256, 0, stream>>>(out);
}

// Round 13
// 11195.557 us; speedup vs baseline: 1.0786x; 1.0531x over previous
//
#include <hip/hip_runtime.h>
#include <hip/hip_bf16.h>
#include <hip/hip_fp16.h>

#define VOCABN 50257
#define EMBEDN 256
#define HIDDENN 256
#define TAGSN 8192
#define SEQN 8192

typedef int i32x4 __attribute__((ext_vector_type(4)));

#define LOG2E 1.4426950408889634f

// fast activations: v_exp_f32 + v_rcp_f32 (1-ulp; noise vs i8 quant error).
// Saturation-safe: x->-inf: exp2(+inf)=inf, rcp(inf)=0; x->+inf: rcp(1)=1.
__device__ __forceinline__ float fast_exp2(float x) {
#if __has_builtin(__builtin_amdgcn_exp2f)
    return __builtin_amdgcn_exp2f(x);
#else
    return __expf(x * 0.6931471805599453f);
#endif
}
__device__ __forceinline__ float fast_rcp(float x) {
#if __has_builtin(__builtin_amdgcn_rcpf)
    return __builtin_amdgcn_rcpf(x);
#else
    return 1.f / x;
#endif
}
__device__ __forceinline__ float sigm(float x) {
    return fast_rcp(1.f + fast_exp2(x * -LOG2E));
}
__device__ __forceinline__ float tanh_f(float x) {
    return fmaf(2.f, fast_rcp(1.f + fast_exp2(x * (-2.f * LOG2E))), -1.f);
}

__device__ __forceinline__ i32x4 mfma_i8(i32x4 a, i32x4 b, i32x4 c) {
#if __has_builtin(__builtin_amdgcn_mfma_i32_16x16x64_i8)
    return __builtin_amdgcn_mfma_i32_16x16x64_i8(a, b, c, 0, 0, 0);
#else
    i32x4 d = c;
    asm("v_mfma_i32_16x16x64_i8 %0, %1, %2, %0" : "+v"(d) : "v"(a), "v"(b));
    return d;
#endif
}

// ---------------------------------------------------------------------------
// prep: WxT[k][o] = W_gate(o)[o&255][k]; bcat[o] = b_gate(o)[o&255]
// ---------------------------------------------------------------------------
__global__ __launch_bounds__(256) void prep_kernel(
    const float* __restrict__ Wf, const float* __restrict__ Wi,
    const float* __restrict__ Wg, const float* __restrict__ Wo,
    const float* __restrict__ bf, const float* __restrict__ bi,
    const float* __restrict__ bg, const float* __restrict__ bo,
    float* __restrict__ WxT, float* __restrict__ bcat)
{
    int idx = blockIdx.x * 256 + threadIdx.x;   // 0..262143
    int k = idx >> 10, o = idx & 1023;
    int g = o >> 8, r = o & 255;
    const float* W = (g == 0) ? Wf : (g == 1) ? Wi : (g == 2) ? Wg : Wo;
    WxT[idx] = W[r * 512 + k];
    if (idx < 1024) {
        const float* b = (g == 0) ? bf : (g == 1) ? bi : (g == 2) ? bg : bo;
        bcat[idx] = b[r];
    }
}

// ---------------------------------------------------------------------------
// xproj[s][o] = sum_k emb[sentence[s]][k] * WxT[k][o] + bcat[o]
// ---------------------------------------------------------------------------
__global__ __launch_bounds__(256) void xproj_kernel(
    const int* __restrict__ sentence, const float* __restrict__ emb,
    const float* __restrict__ WxT, const float* __restrict__ bcat,
    float* __restrict__ xproj)
{
    __shared__ __align__(16) float At[32 * 256];
    const int tid = threadIdx.x;
    const int s0 = blockIdx.y * 32;
    const int o = blockIdx.x * 256 + tid;

#pragma unroll
    for (int i = 0; i < 32; i++) {
        int idx = tid + i * 256;
        int srow = idx >> 8, c = idx & 255;
        At[idx] = emb[(size_t)sentence[s0 + srow] * 256 + c];
    }
    __syncthreads();

    float acc[32];
    float b = bcat[o];
#pragma unroll
    for (int i = 0; i < 32; i++) acc[i] = b;

    for (int k4 = 0; k4 < 64; k4++) {
        float4 w;
        w.x = WxT[(k4 * 4 + 0) * 1024 + o];
        w.y = WxT[(k4 * 4 + 1) * 1024 + o];
        w.z = WxT[(k4 * 4 + 2) * 1024 + o];
        w.w = WxT[(k4 * 4 + 3) * 1024 + o];
#pragma unroll
        for (int i = 0; i < 32; i++) {
            float4 a = *(const float4*)&At[i * 256 + k4 * 4];
            acc[i] += a.x * w.x + a.y * w.y + a.z * w.z + a.w * w.w;
        }
    }
#pragma unroll
    for (int i = 0; i < 32; i++)
        xproj[(size_t)(s0 + i) * 1024 + o] = acc[i];
}

// ---------------------------------------------------------------------------
// Persistent single-workgroup LSTM via int8 MFMA (16x16x64 i8, i32 accum).
// r13 = r12 structure + VALU diet (the kernel is VALU-issue-bound: r12
// measured MFMA 1016 cy/step = i8 floor, VALU 2145 cy/SIMD/step):
//   - activations via v_exp/v_rcp intrinsics (precise-division path was
//     ~10 instrs per gate without -ffast-math)
//   - dequant+xp folded into one fmaf
//   - running xp pointer: the 4 loads use immediate offsets (no per-step
//     64-bit address arithmetic)
//   - 2x unrolled step loop -> static h-buffer indices
// Wave wq owns units [16wq,16wq+16) x 4 gates; weights 16 i8 frags; in-lane
// epilogue (j=row16&3 reg-select, no cross-lane); h staged in LDS, dumped
// every 64 steps (keeps per-step barrier free of VMEM drain).
// ---------------------------------------------------------------------------
__global__ __launch_bounds__(1024)
__attribute__((amdgpu_waves_per_eu(4, 4)))
void lstm_kernel(
    const float* __restrict__ Wf, const float* __restrict__ Wi,
    const float* __restrict__ Wg, const float* __restrict__ Wo,
    const float* __restrict__ xproj, float* __restrict__ h_all)
{
    __shared__ __align__(16) char hb8[2][256];   // dbuf h (i8)
    __shared__ float scLds[4][256];              // rowmax per (gate, unit)
    __shared__ __align__(16) float hstage[64 * 256];  // 64 KiB h staging

    const int t = threadIdx.x;
    const int wq = t >> 6;         // wave 0..15
    const int l = t & 63;          // lane
    const int row16 = l & 15;      // A row (D col replicated)
    const int kg = l >> 4;         // k-group 0..3 (16 bytes each within K=64)

    // ---- one-time setup: per-row maxabs + quantize into 16 i8 frags ----
    i32x4 Areg[16];                // [gate g][kt] = Areg[g*4+kt]
#pragma unroll
    for (int g = 0; g < 4; g++) {
        const float* W = (g == 0) ? Wf : (g == 1) ? Wi : (g == 2) ? Wg : Wo;
        const int row = 16 * wq + row16;
        const float* base = W + row * 512 + 256;   // h-part of the row

        // pass 1: maxabs over this lane's 64 elems (k = kt*64 + kg*16 + j)
        float mx = 0.f;
#pragma unroll
        for (int kt = 0; kt < 4; kt++)
#pragma unroll
            for (int q = 0; q < 4; q++) {
                float4 v4 = *(const float4*)&base[kt * 64 + kg * 16 + 4 * q];
                mx = fmaxf(mx, fmaxf(fmaxf(fabsf(v4.x), fabsf(v4.y)),
                                     fmaxf(fabsf(v4.z), fabsf(v4.w))));
            }
        // combine across the 4 kg lanes (same row16)
        mx = fmaxf(mx, __shfl_xor(mx, 16, 64));
        mx = fmaxf(mx, __shfl_xor(mx, 32, 64));
        mx = fmaxf(mx, 1e-20f);
        const float inv = 127.f / mx;

        // pass 2: quantize & pack (linear k order; A/B share it -> exact dot)
#pragma unroll
        for (int kt = 0; kt < 4; kt++) {
            unsigned int r[4];
#pragma unroll
            for (int q = 0; q < 4; q++) {
                float4 v4 = *(const float4*)&base[kt * 64 + kg * 16 + 4 * q];
                unsigned int b0 = (unsigned int)(__float2int_rn(v4.x * inv) & 255);
                unsigned int b1 = (unsigned int)(__float2int_rn(v4.y * inv) & 255);
                unsigned int b2 = (unsigned int)(__float2int_rn(v4.z * inv) & 255);
                unsigned int b3 = (unsigned int)(__float2int_rn(v4.w * inv) & 255);
                r[q] = b0 | (b1 << 8) | (b2 << 16) | (b3 << 24);
            }
            Areg[g * 4 + kt] = i32x4{(int)r[0], (int)r[1], (int)r[2], (int)r[3]};
        }
        if (kg == 0) scLds[g][row] = mx;           // publish rowmax
    }
    if (t < 256) { hb8[0][t] = 0; hb8[1][t] = 0; }

    // this lane's owned unit (4x redundant across row16>>2)
    const int u = 16 * wq + 4 * kg + (row16 & 3);
    const bool selA = (row16 & 1) != 0, selB = (row16 & 2) != 0;
    const bool writer = (row16 & 12) == 0;
    float cst = 0.f;

    __syncthreads();

    // per-lane dequant scales (rowmax / 127^2) for the 4 gates of unit u
    const float qs = 1.f / (127.f * 127.f);
    float scl[4];
#pragma unroll
    for (int g = 0; g < 4; g++) scl[g] = scLds[g][u] * qs;

    const float* xpp = xproj + u;   // running pointer; +1024/step, imm offsets

    // one LSTM step: read h from hbR, write new h to hbW
    auto step = [&](int s, const char* hbR, char* hbW) {
        float xp0 = xpp[0];
        float xp1 = xpp[256];
        float xp2 = xpp[512];
        float xp3 = xpp[768];
        xpp += 1024;

        i32x4 acc[4];
        const i32x4 z = {0, 0, 0, 0};
        {
            i32x4 b = *(const i32x4*)&hbR[kg * 16];
#pragma unroll
            for (int g = 0; g < 4; g++)
                acc[g] = mfma_i8(Areg[g * 4 + 0], b, z);
        }
#pragma unroll
        for (int kt = 1; kt < 4; kt++) {
            i32x4 b = *(const i32x4*)&hbR[kt * 64 + kg * 16];
#pragma unroll
            for (int g = 0; g < 4; g++)
                acc[g] = mfma_i8(Areg[g * 4 + kt], b, acc[g]);
        }

        // in-lane epilogue: reg-select j = row16&3, dequant+xp via fmaf
        float pre[4];
#pragma unroll
        for (int g = 0; g < 4; g++) {
            int t01 = selA ? acc[g][1] : acc[g][0];
            int t23 = selA ? acc[g][3] : acc[g][2];
            pre[g] = (float)(selB ? t23 : t01);
        }
        float fg = sigm(fmaf(pre[0], scl[0], xp0));
        float ig = sigm(fmaf(pre[1], scl[1], xp1));
        float gg = tanh_f(fmaf(pre[2], scl[2], xp2));
        float og = sigm(fmaf(pre[3], scl[3], xp3));
        cst = fg * cst + ig * gg;
        float h = og * tanh_f(cst);
        if (writer) {
            hstage[(s & 63) * 256 + u] = h;
            hbW[u] = (char)__float2int_rn(h * 127.f);
        }
        if ((s & 63) == 63) {      // dump staged h (amortized VMEM drain)
            __syncthreads();
            float* dst = h_all + (size_t)(s - 63) * 256;
#pragma unroll
            for (int i = 0; i < 16; i++)
                dst[i * 1024 + t] = hstage[i * 1024 + t];
        }
        __syncthreads();
    };

    for (int s = 0; s < SEQN; s += 2) {
        step(s,     hb8[0], hb8[1]);
        step(s + 1, hb8[1], hb8[0]);
    }
}

// ---------------------------------------------------------------------------
// logits[t][v] = h_all[t] . Wtag[v] + btag[v]   (64x64 tile / block, 4x4 micro)
// ---------------------------------------------------------------------------
__global__ __launch_bounds__(256) void logits_kernel(
    const float* __restrict__ h_all, const float* __restrict__ Wtag,
    const float* __restrict__ btag, float* __restrict__ out)
{
    __shared__ __align__(16) float At[64 * 68];
    __shared__ __align__(16) float Bt[64 * 68];
    const int tid = threadIdx.x;
    const int tx = tid & 15, ty = tid >> 4;
    const int t0 = blockIdx.y * 64, v0 = blockIdx.x * 64;
    float acc[4][4] = {};

    for (int kc = 0; kc < 256; kc += 64) {
        __syncthreads();
#pragma unroll
        for (int i = 0; i < 16; i++) {
            int idx = tid + i * 256;
            int rrow = idx >> 6, ccol = idx & 63;
            At[rrow * 68 + ccol] = h_all[(t0 + rrow) * 256 + kc + ccol];
            Bt[rrow * 68 + ccol] = Wtag[(size_t)(v0 + rrow) * 256 + kc + ccol];
        }
        __syncthreads();
#pragma unroll
        for (int k4 = 0; k4 < 16; k4++) {
            float4 av[4], bv[4];
#pragma unroll
            for (int i = 0; i < 4; i++) av[i] = *(const float4*)&At[(ty + 16 * i) * 68 + k4 * 4];
#pragma unroll
            for (int j = 0; j < 4; j++) bv[j] = *(const float4*)&Bt[(tx + 16 * j) * 68 + k4 * 4];
#pragma unroll
            for (int i = 0; i < 4; i++)
#pragma unroll
                for (int j = 0; j < 4; j++)
                    acc[i][j] += av[i].x * bv[j].x + av[i].y * bv[j].y +
                                 av[i].z * bv[j].z + av[i].w * bv[j].w;
        }
    }
#pragma unroll
    for (int j = 0; j < 4; j++) {
        float bb = btag[v0 + tx + 16 * j];
#pragma unroll
        for (int i = 0; i < 4; i++) {
            out[(size_t)(t0 + ty + 16 * i) * TAGSN + v0 + tx + 16 * j] = acc[i][j] + bb;
        }
    }
}

// ---------------------------------------------------------------------------
// in-place row-wise log_softmax over 8192 columns (one block per row)
// ---------------------------------------------------------------------------
__global__ __launch_bounds__(256) void lsm_kernel(float* __restrict__ out)
{
    const int row = blockIdx.x, tid = threadIdx.x;
    float* p = out + (size_t)row * TAGSN;
    float v[32];
#pragma unroll
    for (int j = 0; j < 32; j++) v[j] = p[tid + 256 * j];

    float m = -1e30f;
#pragma unroll
    for (int j = 0; j < 32; j++) m = fmaxf(m, v[j]);
#pragma unroll
    for (int off = 32; off; off >>= 1) m = fmaxf(m, __shfl_xor(m, off, 64));
    __shared__ float red[4];
    if ((tid & 63) == 0) red[tid >> 6] = m;
    __syncthreads();
    m = fmaxf(fmaxf(red[0], red[1]), fmaxf(red[2], red[3]));

    float s = 0.f;
#pragma unroll
    for (int j = 0; j < 32; j++) s += __expf(v[j] - m);
#pragma unroll
    for (int off = 32; off; off >>= 1) s += __shfl_xor(s, off, 64);
    __shared__ float red2[4];
    if ((tid & 63) == 0) red2[tid >> 6] = s;
    __syncthreads();
    s = (red2[0] + red2[1]) + (red2[2] + red2[3]);

    float lse = m + __logf(s);
#pragma unroll
    for (int j = 0; j < 32; j++) p[tid + 256 * j] = v[j] - lse;
}

// ---------------------------------------------------------------------------
extern "C" void kernel_launch(void* const* d_in, const int* in_sizes, int n_in,
                              void* d_out, int out_size, void* d_ws, size_t ws_size,
                              hipStream_t stream)
{
    const int*   sentence = (const int*)d_in[0];
    const float* emb  = (const float*)d_in[1];
    const float* Wf   = (const float*)d_in[2];
    const float* bf   = (const float*)d_in[3];
    const float* Wi   = (const float*)d_in[4];
    const float* bi   = (const float*)d_in[5];
    const float* Wg   = (const float*)d_in[6];
    const float* bg   = (const float*)d_in[7];
    const float* Wo   = (const float*)d_in[8];
    const float* bo   = (const float*)d_in[9];
    const float* Wtag = (const float*)d_in[10];
    const float* btag = (const float*)d_in[11];
    float* out = (float*)d_out;

    char* ws = (char*)d_ws;
    float* WxT   = (float*)(ws);                                      // 1 MiB
    float* bcat  = (float*)(ws + (1u << 20));                         // 4 KiB
    float* xproj = (float*)(ws + (1u << 20) + (1u << 16));            // 32 MiB
    float* h_all = (float*)(ws + (1u << 20) + (1u << 16) + (32u << 20)); // 8 MiB

    prep_kernel<<<1024, 256, 0, stream>>>(Wf, Wi, Wg, Wo, bf, bi, bg, bo, WxT, bcat);
    xproj_kernel<<<dim3(4, 256), 256, 0, stream>>>(sentence, emb, WxT, bcat, xproj);
    lstm_kernel<<<1, 1024, 0, stream>>>(Wf, Wi, Wg, Wo, xproj, h_all);
    logits_kernel<<<dim3(128, 128), 256, 0, stream>>>(h_all, Wtag, btag, out);
    lsm_kernel<<<8192, 256, 0, stream>>>(out);
}

// Round 14
// 9598.248 us; speedup vs baseline: 1.2581x; 1.1664x over previous
//
#include <hip/hip_runtime.h>
#include <hip/hip_bf16.h>
#include <hip/hip_fp16.h>

#define VOCABN 50257
#define EMBEDN 256
#define HIDDENN 256
#define TAGSN 8192
#define SEQN 8192

typedef int i32x4 __attribute__((ext_vector_type(4)));
typedef float f32x4 __attribute__((ext_vector_type(4)));
typedef short short8 __attribute__((ext_vector_type(8)));      // 8 x bf16 frag
typedef unsigned short ushort8v __attribute__((ext_vector_type(8)));

#define LOG2E 1.4426950408889634f

__device__ __forceinline__ float fast_exp2(float x) {
#if __has_builtin(__builtin_amdgcn_exp2f)
    return __builtin_amdgcn_exp2f(x);
#else
    return __expf(x * 0.6931471805599453f);
#endif
}
__device__ __forceinline__ float fast_rcp(float x) {
#if __has_builtin(__builtin_amdgcn_rcpf)
    return __builtin_amdgcn_rcpf(x);
#else
    return 1.f / x;
#endif
}
__device__ __forceinline__ float sigm(float x) {
    return fast_rcp(1.f + fast_exp2(x * -LOG2E));
}
__device__ __forceinline__ float tanh_f(float x) {
    return fmaf(2.f, fast_rcp(1.f + fast_exp2(x * (-2.f * LOG2E))), -1.f);
}
__device__ __forceinline__ unsigned short f2bf(float x) {
    __hip_bfloat16 b = __float2bfloat16(x);
    return __builtin_bit_cast(unsigned short, b);
}

__device__ __forceinline__ i32x4 mfma_i8(i32x4 a, i32x4 b, i32x4 c) {
#if __has_builtin(__builtin_amdgcn_mfma_i32_16x16x64_i8)
    return __builtin_amdgcn_mfma_i32_16x16x64_i8(a, b, c, 0, 0, 0);
#else
    i32x4 d = c;
    asm("v_mfma_i32_16x16x64_i8 %0, %1, %2, %0" : "+v"(d) : "v"(a), "v"(b));
    return d;
#endif
}

// ---------------------------------------------------------------------------
// prep: WxT[k][o] = W_gate(o)[o&255][k]; bcat[o] = b_gate(o)[o&255]
// ---------------------------------------------------------------------------
__global__ __launch_bounds__(256) void prep_kernel(
    const float* __restrict__ Wf, const float* __restrict__ Wi,
    const float* __restrict__ Wg, const float* __restrict__ Wo,
    const float* __restrict__ bf, const float* __restrict__ bi,
    const float* __restrict__ bg, const float* __restrict__ bo,
    float* __restrict__ WxT, float* __restrict__ bcat)
{
    int idx = blockIdx.x * 256 + threadIdx.x;   // 0..262143
    int k = idx >> 10, o = idx & 1023;
    int g = o >> 8, r = o & 255;
    const float* W = (g == 0) ? Wf : (g == 1) ? Wi : (g == 2) ? Wg : Wo;
    WxT[idx] = W[r * 512 + k];
    if (idx < 1024) {
        const float* b = (g == 0) ? bf : (g == 1) ? bi : (g == 2) ? bg : bo;
        bcat[idx] = b[r];
    }
}

// ---------------------------------------------------------------------------
// tagprep: WtagB = bf16(Wtag)   (4 MB, L3-resident for the logits GEMM)
// ---------------------------------------------------------------------------
__global__ __launch_bounds__(256) void tagprep_kernel(
    const float* __restrict__ Wtag, unsigned short* __restrict__ WtagB)
{
    int idx = (blockIdx.x * 256 + threadIdx.x) * 4;   // grid 2048 -> 2M elems
    float4 v = *(const float4*)&Wtag[idx];
    ushort4 o;
    o.x = f2bf(v.x); o.y = f2bf(v.y); o.z = f2bf(v.z); o.w = f2bf(v.w);
    *(ushort4*)&WtagB[idx] = o;
}

// ---------------------------------------------------------------------------
// xproj[s][o] = sum_k emb[sentence[s]][k] * WxT[k][o] + bcat[o]
// ---------------------------------------------------------------------------
__global__ __launch_bounds__(256) void xproj_kernel(
    const int* __restrict__ sentence, const float* __restrict__ emb,
    const float* __restrict__ WxT, const float* __restrict__ bcat,
    float* __restrict__ xproj)
{
    __shared__ __align__(16) float At[32 * 256];
    const int tid = threadIdx.x;
    const int s0 = blockIdx.y * 32;
    const int o = blockIdx.x * 256 + tid;

#pragma unroll
    for (int i = 0; i < 32; i++) {
        int idx = tid + i * 256;
        int srow = idx >> 8, c = idx & 255;
        At[idx] = emb[(size_t)sentence[s0 + srow] * 256 + c];
    }
    __syncthreads();

    float acc[32];
    float b = bcat[o];
#pragma unroll
    for (int i = 0; i < 32; i++) acc[i] = b;

    for (int k4 = 0; k4 < 64; k4++) {
        float4 w;
        w.x = WxT[(k4 * 4 + 0) * 1024 + o];
        w.y = WxT[(k4 * 4 + 1) * 1024 + o];
        w.z = WxT[(k4 * 4 + 2) * 1024 + o];
        w.w = WxT[(k4 * 4 + 3) * 1024 + o];
#pragma unroll
        for (int i = 0; i < 32; i++) {
            float4 a = *(const float4*)&At[i * 256 + k4 * 4];
            acc[i] += a.x * w.x + a.y * w.y + a.z * w.z + a.w * w.w;
        }
    }
#pragma unroll
    for (int i = 0; i < 32; i++)
        xproj[(size_t)(s0 + i) * 1024 + o] = acc[i];
}

// ---------------------------------------------------------------------------
// Persistent single-workgroup LSTM via int8 MFMA (16x16x64 i8, i32 accum).
// r14 = r13 unchanged except h is stored to global as bf16 (hB) for the
// MFMA logits GEMM (halves h traffic; bf16 err 2^-9 << i8 path error).
// ---------------------------------------------------------------------------
__global__ __launch_bounds__(1024)
__attribute__((amdgpu_waves_per_eu(4, 4)))
void lstm_kernel(
    const float* __restrict__ Wf, const float* __restrict__ Wi,
    const float* __restrict__ Wg, const float* __restrict__ Wo,
    const float* __restrict__ xproj, unsigned short* __restrict__ hB)
{
    __shared__ __align__(16) char hb8[2][256];           // dbuf h (i8)
    __shared__ float scLds[4][256];                      // rowmax per (gate, unit)
    __shared__ __align__(16) unsigned short hstage[64 * 256];  // 32 KiB h staging (bf16)

    const int t = threadIdx.x;
    const int wq = t >> 6;         // wave 0..15
    const int l = t & 63;          // lane
    const int row16 = l & 15;      // A row (D col replicated)
    const int kg = l >> 4;         // k-group 0..3 (16 bytes each within K=64)

    // ---- one-time setup: per-row maxabs + quantize into 16 i8 frags ----
    i32x4 Areg[16];                // [gate g][kt] = Areg[g*4+kt]
#pragma unroll
    for (int g = 0; g < 4; g++) {
        const float* W = (g == 0) ? Wf : (g == 1) ? Wi : (g == 2) ? Wg : Wo;
        const int row = 16 * wq + row16;
        const float* base = W + row * 512 + 256;   // h-part of the row

        float mx = 0.f;
#pragma unroll
        for (int kt = 0; kt < 4; kt++)
#pragma unroll
            for (int q = 0; q < 4; q++) {
                float4 v4 = *(const float4*)&base[kt * 64 + kg * 16 + 4 * q];
                mx = fmaxf(mx, fmaxf(fmaxf(fabsf(v4.x), fabsf(v4.y)),
                                     fmaxf(fabsf(v4.z), fabsf(v4.w))));
            }
        mx = fmaxf(mx, __shfl_xor(mx, 16, 64));
        mx = fmaxf(mx, __shfl_xor(mx, 32, 64));
        mx = fmaxf(mx, 1e-20f);
        const float inv = 127.f / mx;

#pragma unroll
        for (int kt = 0; kt < 4; kt++) {
            unsigned int r[4];
#pragma unroll
            for (int q = 0; q < 4; q++) {
                float4 v4 = *(const float4*)&base[kt * 64 + kg * 16 + 4 * q];
                unsigned int b0 = (unsigned int)(__float2int_rn(v4.x * inv) & 255);
                unsigned int b1 = (unsigned int)(__float2int_rn(v4.y * inv) & 255);
                unsigned int b2 = (unsigned int)(__float2int_rn(v4.z * inv) & 255);
                unsigned int b3 = (unsigned int)(__float2int_rn(v4.w * inv) & 255);
                r[q] = b0 | (b1 << 8) | (b2 << 16) | (b3 << 24);
            }
            Areg[g * 4 + kt] = i32x4{(int)r[0], (int)r[1], (int)r[2], (int)r[3]};
        }
        if (kg == 0) scLds[g][row] = mx;
    }
    if (t < 256) { hb8[0][t] = 0; hb8[1][t] = 0; }

    const int u = 16 * wq + 4 * kg + (row16 & 3);
    const bool selA = (row16 & 1) != 0, selB = (row16 & 2) != 0;
    const bool writer = (row16 & 12) == 0;
    float cst = 0.f;

    __syncthreads();

    const float qs = 1.f / (127.f * 127.f);
    float scl[4];
#pragma unroll
    for (int g = 0; g < 4; g++) scl[g] = scLds[g][u] * qs;

    const float* xpp = xproj + u;   // running pointer; +1024/step, imm offsets

    auto step = [&](int s, const char* hbR, char* hbW) {
        float xp0 = xpp[0];
        float xp1 = xpp[256];
        float xp2 = xpp[512];
        float xp3 = xpp[768];
        xpp += 1024;

        i32x4 acc[4];
        const i32x4 z = {0, 0, 0, 0};
        {
            i32x4 b = *(const i32x4*)&hbR[kg * 16];
#pragma unroll
            for (int g = 0; g < 4; g++)
                acc[g] = mfma_i8(Areg[g * 4 + 0], b, z);
        }
#pragma unroll
        for (int kt = 1; kt < 4; kt++) {
            i32x4 b = *(const i32x4*)&hbR[kt * 64 + kg * 16];
#pragma unroll
            for (int g = 0; g < 4; g++)
                acc[g] = mfma_i8(Areg[g * 4 + kt], b, acc[g]);
        }

        float pre[4];
#pragma unroll
        for (int g = 0; g < 4; g++) {
            int t01 = selA ? acc[g][1] : acc[g][0];
            int t23 = selA ? acc[g][3] : acc[g][2];
            pre[g] = (float)(selB ? t23 : t01);
        }
        float fg = sigm(fmaf(pre[0], scl[0], xp0));
        float ig = sigm(fmaf(pre[1], scl[1], xp1));
        float gg = tanh_f(fmaf(pre[2], scl[2], xp2));
        float og = sigm(fmaf(pre[3], scl[3], xp3));
        cst = fg * cst + ig * gg;
        float h = og * tanh_f(cst);
        if (writer) {
            hstage[(s & 63) * 256 + u] = f2bf(h);
            hbW[u] = (char)__float2int_rn(h * 127.f);
        }
        if ((s & 63) == 63) {      // dump staged h (amortized VMEM drain)
            __syncthreads();
            ushort4* dst = (ushort4*)(hB + (size_t)(s - 63) * 256);
            const ushort4* srcp = (const ushort4*)hstage;
#pragma unroll
            for (int i = 0; i < 4; i++)
                dst[t + i * 1024] = srcp[t + i * 1024];
        }
        __syncthreads();
    };

    for (int s = 0; s < SEQN; s += 2) {
        step(s,     hb8[0], hb8[1]);
        step(s + 1, hb8[1], hb8[0]);
    }
}

// ---------------------------------------------------------------------------
// logits[t][v] = h[t] . Wtag[v] + btag[v]  via bf16 MFMA (16x16x32).
// Block = 256 thr (4 waves), tile 128t x 64v, K=256 staged in LDS.
// LDS rows padded to 264 ushorts (bank map 4r+c -> 2-way, free).
// Frag layouts: B verified in-kernel since r3 (k=(l>>4)*8+j, col=l&15);
// A is the operand-symmetric twin (row=l&15, k=(l>>4)*8+j); D per m89.
// ---------------------------------------------------------------------------
__global__ __launch_bounds__(256) void logits_kernel(
    const unsigned short* __restrict__ hB, const unsigned short* __restrict__ WtagB,
    const float* __restrict__ btag, float* __restrict__ out)
{
    __shared__ __align__(16) unsigned short Ah[128 * 264];  // 66 KiB
    __shared__ __align__(16) unsigned short Bw[64 * 264];   // 33 KiB

    const int tid = threadIdx.x;
    const int v0 = blockIdx.x * 64, t0 = blockIdx.y * 128;

    // stage h strip (contiguous 32768 ushorts) and Wtag tile (16384)
    {
        const ushort8v* srcA = (const ushort8v*)(hB + (size_t)t0 * 256);
        ushort8v* dstA = (ushort8v*)Ah;
#pragma unroll
        for (int i = 0; i < 16; i++) {
            int idx = tid + i * 256;          // 0..4095
            int row = idx >> 5, c8 = idx & 31;
            dstA[row * 33 + c8] = srcA[idx];
        }
        const ushort8v* srcB = (const ushort8v*)(WtagB + (size_t)v0 * 256);
        ushort8v* dstB = (ushort8v*)Bw;
#pragma unroll
        for (int i = 0; i < 8; i++) {
            int idx = tid + i * 256;          // 0..2047
            int row = idx >> 5, c8 = idx & 31;
            dstB[row * 33 + c8] = srcB[idx];
        }
    }
    __syncthreads();

    const int wave = tid >> 6, l = tid & 63;
    const int r16 = l & 15, kg = l >> 4;

    f32x4 acc[2][4];
#pragma unroll
    for (int p = 0; p < 2; p++)
#pragma unroll
        for (int c = 0; c < 4; c++) acc[p][c] = f32x4{0.f, 0.f, 0.f, 0.f};

#pragma unroll
    for (int ks = 0; ks < 8; ks++) {
        short8 a0 = *(const short8*)&Ah[(wave * 32 + r16) * 264 + ks * 32 + kg * 8];
        short8 a1 = *(const short8*)&Ah[(wave * 32 + 16 + r16) * 264 + ks * 32 + kg * 8];
#pragma unroll
        for (int c = 0; c < 4; c++) {
            short8 b = *(const short8*)&Bw[(c * 16 + r16) * 264 + ks * 32 + kg * 8];
            acc[0][c] = __builtin_amdgcn_mfma_f32_16x16x32_bf16(a0, b, acc[0][c], 0, 0, 0);
            acc[1][c] = __builtin_amdgcn_mfma_f32_16x16x32_bf16(a1, b, acc[1][c], 0, 0, 0);
        }
    }

    float bb[4];
#pragma unroll
    for (int c = 0; c < 4; c++) bb[c] = btag[v0 + c * 16 + r16];

#pragma unroll
    for (int p = 0; p < 2; p++)
#pragma unroll
        for (int c = 0; c < 4; c++)
#pragma unroll
            for (int reg = 0; reg < 4; reg++) {
                int row = t0 + wave * 32 + p * 16 + kg * 4 + reg;
                out[(size_t)row * TAGSN + v0 + c * 16 + r16] = acc[p][c][reg] + bb[c];
            }
}

// ---------------------------------------------------------------------------
// in-place row-wise log_softmax over 8192 columns (one block per row), float4
// ---------------------------------------------------------------------------
__global__ __launch_bounds__(256) void lsm_kernel(float* __restrict__ out)
{
    const int row = blockIdx.x, tid = threadIdx.x;
    float* p = out + (size_t)row * TAGSN;
    float4* p4 = (float4*)p;
    float4 v[8];
#pragma unroll
    for (int j = 0; j < 8; j++) v[j] = p4[tid + 256 * j];

    float m = -1e30f;
#pragma unroll
    for (int j = 0; j < 8; j++)
        m = fmaxf(m, fmaxf(fmaxf(v[j].x, v[j].y), fmaxf(v[j].z, v[j].w)));
#pragma unroll
    for (int off = 32; off; off >>= 1) m = fmaxf(m, __shfl_xor(m, off, 64));
    __shared__ float red[4];
    if ((tid & 63) == 0) red[tid >> 6] = m;
    __syncthreads();
    m = fmaxf(fmaxf(red[0], red[1]), fmaxf(red[2], red[3]));

    float s = 0.f;
#pragma unroll
    for (int j = 0; j < 8; j++) {
        s += __expf(v[j].x - m) + __expf(v[j].y - m)
           + __expf(v[j].z - m) + __expf(v[j].w - m);
    }
#pragma unroll
    for (int off = 32; off; off >>= 1) s += __shfl_xor(s, off, 64);
    __shared__ float red2[4];
    if ((tid & 63) == 0) red2[tid >> 6] = s;
    __syncthreads();
    s = (red2[0] + red2[1]) + (red2[2] + red2[3]);

    float lse = m + __logf(s);
#pragma unroll
    for (int j = 0; j < 8; j++) {
        float4 o = v[j];
        o.x -= lse; o.y -= lse; o.z -= lse; o.w -= lse;
        p4[tid + 256 * j] = o;
    }
}

// ---------------------------------------------------------------------------
extern "C" void kernel_launch(void* const* d_in, const int* in_sizes, int n_in,
                              void* d_out, int out_size, void* d_ws, size_t ws_size,
                              hipStream_t stream)
{
    const int*   sentence = (const int*)d_in[0];
    const float* emb  = (const float*)d_in[1];
    const float* Wf   = (const float*)d_in[2];
    const float* bf   = (const float*)d_in[3];
    const float* Wi   = (const float*)d_in[4];
    const float* bi   = (const float*)d_in[5];
    const float* Wg   = (const float*)d_in[6];
    const float* bg   = (const float*)d_in[7];
    const float* Wo   = (const float*)d_in[8];
    const float* bo   = (const float*)d_in[9];
    const float* Wtag = (const float*)d_in[10];
    const float* btag = (const float*)d_in[11];
    float* out = (float*)d_out;

    char* ws = (char*)d_ws;
    float* WxT   = (float*)(ws);                                      // 1 MiB
    float* bcat  = (float*)(ws + (1u << 20));                         // 4 KiB
    float* xproj = (float*)(ws + (1u << 20) + (1u << 16));            // 32 MiB
    unsigned short* hB    = (unsigned short*)(ws + (1u << 20) + (1u << 16) + (32u << 20));       // 4 MiB
    unsigned short* WtagB = (unsigned short*)(ws + (1u << 20) + (1u << 16) + (36u << 20));       // 4 MiB

    prep_kernel<<<1024, 256, 0, stream>>>(Wf, Wi, Wg, Wo, bf, bi, bg, bo, WxT, bcat);
    tagprep_kernel<<<2048, 256, 0, stream>>>(Wtag, WtagB);
    xproj_kernel<<<dim3(4, 256), 256, 0, stream>>>(sentence, emb, WxT, bcat, xproj);
    lstm_kernel<<<1, 1024, 0, stream>>>(Wf, Wi, Wg, Wo, xproj, hB);
    logits_kernel<<<dim3(128, 64), 256, 0, stream>>>(hB, WtagB, btag, out);
    lsm_kernel<<<8192, 256, 0, stream>>>(out);
}

// Round 15
// 7393.417 us; speedup vs baseline: 1.6333x; 1.2982x over previous
//
#include <hip/hip_runtime.h>
#include <hip/hip_bf16.h>
#include <hip/hip_fp16.h>

#define VOCABN 50257
#define EMBEDN 256
#define HIDDENN 256
#define TAGSN 8192
#define SEQN 8192

typedef int i32x4 __attribute__((ext_vector_type(4)));
typedef float f32x4 __attribute__((ext_vector_type(4)));
typedef short short8 __attribute__((ext_vector_type(8)));      // 8 x bf16 frag
typedef unsigned short ushort8v __attribute__((ext_vector_type(8)));

#define LOG2E 1.4426950408889634f

__device__ __forceinline__ float fast_exp2(float x) {
#if __has_builtin(__builtin_amdgcn_exp2f)
    return __builtin_amdgcn_exp2f(x);
#else
    return __expf(x * 0.6931471805599453f);
#endif
}
__device__ __forceinline__ float fast_rcp(float x) {
#if __has_builtin(__builtin_amdgcn_rcpf)
    return __builtin_amdgcn_rcpf(x);
#else
    return 1.f / x;
#endif
}
__device__ __forceinline__ float sigm(float x) {
    return fast_rcp(1.f + fast_exp2(x * -LOG2E));
}
__device__ __forceinline__ float tanh_f(float x) {
    return fmaf(2.f, fast_rcp(1.f + fast_exp2(x * (-2.f * LOG2E))), -1.f);
}
__device__ __forceinline__ unsigned short f2bf(float x) {
    __hip_bfloat16 b = __float2bfloat16(x);
    return __builtin_bit_cast(unsigned short, b);
}

__device__ __forceinline__ i32x4 mfma_i8(i32x4 a, i32x4 b, i32x4 c) {
#if __has_builtin(__builtin_amdgcn_mfma_i32_16x16x64_i8)
    return __builtin_amdgcn_mfma_i32_16x16x64_i8(a, b, c, 0, 0, 0);
#else
    i32x4 d = c;
    asm("v_mfma_i32_16x16x64_i8 %0, %1, %2, %0" : "+v"(d) : "v"(a), "v"(b));
    return d;
#endif
}

// ---------------------------------------------------------------------------
// prep: WxT[k][o] = W_gate(o)[o&255][k]; bcat[o] = b_gate(o)[o&255]
// ---------------------------------------------------------------------------
__global__ __launch_bounds__(256) void prep_kernel(
    const float* __restrict__ Wf, const float* __restrict__ Wi,
    const float* __restrict__ Wg, const float* __restrict__ Wo,
    const float* __restrict__ bf, const float* __restrict__ bi,
    const float* __restrict__ bg, const float* __restrict__ bo,
    float* __restrict__ WxT, float* __restrict__ bcat)
{
    int idx = blockIdx.x * 256 + threadIdx.x;   // 0..262143
    int k = idx >> 10, o = idx & 1023;
    int g = o >> 8, r = o & 255;
    const float* W = (g == 0) ? Wf : (g == 1) ? Wi : (g == 2) ? Wg : Wo;
    WxT[idx] = W[r * 512 + k];
    if (idx < 1024) {
        const float* b = (g == 0) ? bf : (g == 1) ? bi : (g == 2) ? bg : bo;
        bcat[idx] = b[r];
    }
}

// ---------------------------------------------------------------------------
// tagprep: WtagB = bf16(Wtag)   (4 MB, L3-resident for the logits GEMM)
// ---------------------------------------------------------------------------
__global__ __launch_bounds__(256) void tagprep_kernel(
    const float* __restrict__ Wtag, unsigned short* __restrict__ WtagB)
{
    int idx = (blockIdx.x * 256 + threadIdx.x) * 4;   // grid 2048 -> 2M elems
    float4 v = *(const float4*)&Wtag[idx];
    ushort4 o;
    o.x = f2bf(v.x); o.y = f2bf(v.y); o.z = f2bf(v.z); o.w = f2bf(v.w);
    *(ushort4*)&WtagB[idx] = o;
}

// ---------------------------------------------------------------------------
// xproj[s][o] = sum_k emb[sentence[s]][k] * WxT[k][o] + bcat[o]
// ---------------------------------------------------------------------------
__global__ __launch_bounds__(256) void xproj_kernel(
    const int* __restrict__ sentence, const float* __restrict__ emb,
    const float* __restrict__ WxT, const float* __restrict__ bcat,
    float* __restrict__ xproj)
{
    __shared__ __align__(16) float At[32 * 256];
    const int tid = threadIdx.x;
    const int s0 = blockIdx.y * 32;
    const int o = blockIdx.x * 256 + tid;

#pragma unroll
    for (int i = 0; i < 32; i++) {
        int idx = tid + i * 256;
        int srow = idx >> 8, c = idx & 255;
        At[idx] = emb[(size_t)sentence[s0 + srow] * 256 + c];
    }
    __syncthreads();

    float acc[32];
    float b = bcat[o];
#pragma unroll
    for (int i = 0; i < 32; i++) acc[i] = b;

    for (int k4 = 0; k4 < 64; k4++) {
        float4 w;
        w.x = WxT[(k4 * 4 + 0) * 1024 + o];
        w.y = WxT[(k4 * 4 + 1) * 1024 + o];
        w.z = WxT[(k4 * 4 + 2) * 1024 + o];
        w.w = WxT[(k4 * 4 + 3) * 1024 + o];
#pragma unroll
        for (int i = 0; i < 32; i++) {
            float4 a = *(const float4*)&At[i * 256 + k4 * 4];
            acc[i] += a.x * w.x + a.y * w.y + a.z * w.z + a.w * w.w;
        }
    }
#pragma unroll
    for (int i = 0; i < 32; i++)
        xproj[(size_t)(s0 + i) * 1024 + o] = acc[i];
}

// ---------------------------------------------------------------------------
// Persistent single-workgroup LSTM via int8 MFMA (16x16x64 i8, i32 accum).
// r15: minimum-redundancy epilogue. All 16 waves do their MFMA share and
// publish raw i32 preacts (writer lanes, one masked ds_write_b128/wave:
// preF[u] = {acc_f,acc_i,acc_g,acc_o}); bar1; ONLY waves 0-3 (one per SIMD,
// 256 lanes = exactly 1 lane/unit, zero redundancy) run dequant+xp+
// activations+cell update and write h (i8 + bf16 stage); bar2.
// Rationale (r14 counters): epilogue ran 8x redundant across 1024 lanes;
// trans (10/thread/step x 4 waves/SIMD) + VALU ~670 cy/SIMD of lockstep
// phase time. Consolidation cuts per-SIMD epilogue issue ~4x for the cost
// of one extra barrier.
// ---------------------------------------------------------------------------
__global__ __launch_bounds__(1024)
__attribute__((amdgpu_waves_per_eu(4, 4)))
void lstm_kernel(
    const float* __restrict__ Wf, const float* __restrict__ Wi,
    const float* __restrict__ Wg, const float* __restrict__ Wo,
    const float* __restrict__ xproj, unsigned short* __restrict__ hB)
{
    __shared__ __align__(16) char hb8[2][256];           // dbuf h (i8)
    __shared__ float scLds[4][256];                      // rowmax per (gate, unit)
    __shared__ __align__(16) int preF[256][4];           // 4 KiB raw i32 preacts
    __shared__ __align__(16) unsigned short hstage[64 * 256];  // 32 KiB h staging (bf16)

    const int t = threadIdx.x;
    const int wq = t >> 6;         // wave 0..15
    const int l = t & 63;          // lane
    const int row16 = l & 15;      // A row (D col replicated)
    const int kg = l >> 4;         // k-group 0..3 (16 bytes each within K=64)

    // ---- one-time setup: per-row maxabs + quantize into 16 i8 frags ----
    i32x4 Areg[16];                // [gate g][kt] = Areg[g*4+kt]
#pragma unroll
    for (int g = 0; g < 4; g++) {
        const float* W = (g == 0) ? Wf : (g == 1) ? Wi : (g == 2) ? Wg : Wo;
        const int row = 16 * wq + row16;
        const float* base = W + row * 512 + 256;   // h-part of the row

        float mx = 0.f;
#pragma unroll
        for (int kt = 0; kt < 4; kt++)
#pragma unroll
            for (int q = 0; q < 4; q++) {
                float4 v4 = *(const float4*)&base[kt * 64 + kg * 16 + 4 * q];
                mx = fmaxf(mx, fmaxf(fmaxf(fabsf(v4.x), fabsf(v4.y)),
                                     fmaxf(fabsf(v4.z), fabsf(v4.w))));
            }
        mx = fmaxf(mx, __shfl_xor(mx, 16, 64));
        mx = fmaxf(mx, __shfl_xor(mx, 32, 64));
        mx = fmaxf(mx, 1e-20f);
        const float inv = 127.f / mx;

#pragma unroll
        for (int kt = 0; kt < 4; kt++) {
            unsigned int r[4];
#pragma unroll
            for (int q = 0; q < 4; q++) {
                float4 v4 = *(const float4*)&base[kt * 64 + kg * 16 + 4 * q];
                unsigned int b0 = (unsigned int)(__float2int_rn(v4.x * inv) & 255);
                unsigned int b1 = (unsigned int)(__float2int_rn(v4.y * inv) & 255);
                unsigned int b2 = (unsigned int)(__float2int_rn(v4.z * inv) & 255);
                unsigned int b3 = (unsigned int)(__float2int_rn(v4.w * inv) & 255);
                r[q] = b0 | (b1 << 8) | (b2 << 16) | (b3 << 24);
            }
            Areg[g * 4 + kt] = i32x4{(int)r[0], (int)r[1], (int)r[2], (int)r[3]};
        }
        if (kg == 0) scLds[g][row] = mx;
    }
    if (t < 256) { hb8[0][t] = 0; hb8[1][t] = 0; }

    // publish constants (all waves)
    const int u_sel = 16 * wq + 4 * kg + (row16 & 3);
    const bool selA = (row16 & 1) != 0, selB = (row16 & 2) != 0;
    const bool writer = (row16 & 12) == 0;

    // epilogue role: waves 0..3 (one per SIMD), lane l owns unit uu
    const bool epi = (wq < 4);
    const int uu = 64 * wq + l;

    __syncthreads();

    float cst = 0.f;
    float sclE[4];
    const float qs = 1.f / (127.f * 127.f);
    if (epi) {
#pragma unroll
        for (int g = 0; g < 4; g++) sclE[g] = scLds[g][uu] * qs;
    }
    const float* xpp = xproj + uu;   // epilogue waves only; +1024/step

    auto step = [&](int s, const char* hbR, char* hbW) {
        float xp0, xp1, xp2, xp3;
        if (epi) {                  // issue early; hidden under MFMA phase
            xp0 = xpp[0];
            xp1 = xpp[256];
            xp2 = xpp[512];
            xp3 = xpp[768];
            xpp += 1024;
        }

        i32x4 acc[4];
        const i32x4 z = {0, 0, 0, 0};
        {
            i32x4 b = *(const i32x4*)&hbR[kg * 16];
#pragma unroll
            for (int g = 0; g < 4; g++)
                acc[g] = mfma_i8(Areg[g * 4 + 0], b, z);
        }
#pragma unroll
        for (int kt = 1; kt < 4; kt++) {
            i32x4 b = *(const i32x4*)&hbR[kt * 64 + kg * 16];
#pragma unroll
            for (int g = 0; g < 4; g++)
                acc[g] = mfma_i8(Areg[g * 4 + kt], b, acc[g]);
        }

        // publish raw preacts: writer lanes, one i32x4 per unit
        int pv[4];
#pragma unroll
        for (int g = 0; g < 4; g++) {
            int t01 = selA ? acc[g][1] : acc[g][0];
            int t23 = selA ? acc[g][3] : acc[g][2];
            pv[g] = selB ? t23 : t01;
        }
        if (writer)
            *(i32x4*)&preF[u_sel][0] = i32x4{pv[0], pv[1], pv[2], pv[3]};
        __syncthreads();   // bar1: preF complete

        if (epi) {
            i32x4 pp = *(const i32x4*)&preF[uu][0];
            float fg = sigm(fmaf((float)pp[0], sclE[0], xp0));
            float ig = sigm(fmaf((float)pp[1], sclE[1], xp1));
            float gg = tanh_f(fmaf((float)pp[2], sclE[2], xp2));
            float og = sigm(fmaf((float)pp[3], sclE[3], xp3));
            cst = fg * cst + ig * gg;
            float h = og * tanh_f(cst);
            hbW[uu] = (char)__float2int_rn(h * 127.f);
            hstage[(s & 63) * 256 + uu] = f2bf(h);
        }
        __syncthreads();   // bar2: new h visible

        if ((s & 63) == 63) {       // dump staged h (amortized VMEM drain)
            ushort4* dst = (ushort4*)(hB + (size_t)(s - 63) * 256);
            const ushort4* srcp = (const ushort4*)hstage;
#pragma unroll
            for (int i = 0; i < 4; i++)
                dst[t + i * 1024] = srcp[t + i * 1024];
        }
    };

    for (int s = 0; s < SEQN; s += 2) {
        step(s,     hb8[0], hb8[1]);
        step(s + 1, hb8[1], hb8[0]);
    }
}

// ---------------------------------------------------------------------------
// logits[t][v] = h[t] . Wtag[v] + btag[v]  via bf16 MFMA (16x16x32).
// ---------------------------------------------------------------------------
__global__ __launch_bounds__(256) void logits_kernel(
    const unsigned short* __restrict__ hB, const unsigned short* __restrict__ WtagB,
    const float* __restrict__ btag, float* __restrict__ out)
{
    __shared__ __align__(16) unsigned short Ah[128 * 264];  // 66 KiB
    __shared__ __align__(16) unsigned short Bw[64 * 264];   // 33 KiB

    const int tid = threadIdx.x;
    const int v0 = blockIdx.x * 64, t0 = blockIdx.y * 128;

    {
        const ushort8v* srcA = (const ushort8v*)(hB + (size_t)t0 * 256);
        ushort8v* dstA = (ushort8v*)Ah;
#pragma unroll
        for (int i = 0; i < 16; i++) {
            int idx = tid + i * 256;          // 0..4095
            int row = idx >> 5, c8 = idx & 31;
            dstA[row * 33 + c8] = srcA[idx];
        }
        const ushort8v* srcB = (const ushort8v*)(WtagB + (size_t)v0 * 256);
        ushort8v* dstB = (ushort8v*)Bw;
#pragma unroll
        for (int i = 0; i < 8; i++) {
            int idx = tid + i * 256;          // 0..2047
            int row = idx >> 5, c8 = idx & 31;
            dstB[row * 33 + c8] = srcB[idx];
        }
    }
    __syncthreads();

    const int wave = tid >> 6, l = tid & 63;
    const int r16 = l & 15, kg = l >> 4;

    f32x4 acc[2][4];
#pragma unroll
    for (int p = 0; p < 2; p++)
#pragma unroll
        for (int c = 0; c < 4; c++) acc[p][c] = f32x4{0.f, 0.f, 0.f, 0.f};

#pragma unroll
    for (int ks = 0; ks < 8; ks++) {
        short8 a0 = *(const short8*)&Ah[(wave * 32 + r16) * 264 + ks * 32 + kg * 8];
        short8 a1 = *(const short8*)&Ah[(wave * 32 + 16 + r16) * 264 + ks * 32 + kg * 8];
#pragma unroll
        for (int c = 0; c < 4; c++) {
            short8 b = *(const short8*)&Bw[(c * 16 + r16) * 264 + ks * 32 + kg * 8];
            acc[0][c] = __builtin_amdgcn_mfma_f32_16x16x32_bf16(a0, b, acc[0][c], 0, 0, 0);
            acc[1][c] = __builtin_amdgcn_mfma_f32_16x16x32_bf16(a1, b, acc[1][c], 0, 0, 0);
        }
    }

    float bb[4];
#pragma unroll
    for (int c = 0; c < 4; c++) bb[c] = btag[v0 + c * 16 + r16];

#pragma unroll
    for (int p = 0; p < 2; p++)
#pragma unroll
        for (int c = 0; c < 4; c++)
#pragma unroll
            for (int reg = 0; reg < 4; reg++) {
                int row = t0 + wave * 32 + p * 16 + kg * 4 + reg;
                out[(size_t)row * TAGSN + v0 + c * 16 + r16] = acc[p][c][reg] + bb[c];
            }
}

// ---------------------------------------------------------------------------
// in-place row-wise log_softmax over 8192 columns (one block per row), float4
// ---------------------------------------------------------------------------
__global__ __launch_bounds__(256) void lsm_kernel(float* __restrict__ out)
{
    const int row = blockIdx.x, tid = threadIdx.x;
    float* p = out + (size_t)row * TAGSN;
    float4* p4 = (float4*)p;
    float4 v[8];
#pragma unroll
    for (int j = 0; j < 8; j++) v[j] = p4[tid + 256 * j];

    float m = -1e30f;
#pragma unroll
    for (int j = 0; j < 8; j++)
        m = fmaxf(m, fmaxf(fmaxf(v[j].x, v[j].y), fmaxf(v[j].z, v[j].w)));
#pragma unroll
    for (int off = 32; off; off >>= 1) m = fmaxf(m, __shfl_xor(m, off, 64));
    __shared__ float red[4];
    if ((tid & 63) == 0) red[tid >> 6] = m;
    __syncthreads();
    m = fmaxf(fmaxf(red[0], red[1]), fmaxf(red[2], red[3]));

    float s = 0.f;
#pragma unroll
    for (int j = 0; j < 8; j++) {
        s += __expf(v[j].x - m) + __expf(v[j].y - m)
           + __expf(v[j].z - m) + __expf(v[j].w - m);
    }
#pragma unroll
    for (int off = 32; off; off >>= 1) s += __shfl_xor(s, off, 64);
    __shared__ float red2[4];
    if ((tid & 63) == 0) red2[tid >> 6] = s;
    __syncthreads();
    s = (red2[0] + red2[1]) + (red2[2] + red2[3]);

    float lse = m + __logf(s);
#pragma unroll
    for (int j = 0; j < 8; j++) {
        float4 o = v[j];
        o.x -= lse; o.y -= lse; o.z -= lse; o.w -= lse;
        p4[tid + 256 * j] = o;
    }
}

// ---------------------------------------------------------------------------
extern "C" void kernel_launch(void* const* d_in, const int* in_sizes, int n_in,
                              void* d_out, int out_size, void* d_ws, size_t ws_size,
                              hipStream_t stream)
{
    const int*   sentence = (const int*)d_in[0];
    const float* emb  = (const float*)d_in[1];
    const float* Wf   = (const float*)d_in[2];
    const float* bf   = (const float*)d_in[3];
    const float* Wi   = (const float*)d_in[4];
    const float* bi   = (const float*)d_in[5];
    const float* Wg   = (const float*)d_in[6];
    const float* bg   = (const float*)d_in[7];
    const float* Wo   = (const float*)d_in[8];
    const float* bo   = (const float*)d_in[9];
    const float* Wtag = (const float*)d_in[10];
    const float* btag = (const float*)d_in[11];
    float* out = (float*)d_out;

    char* ws = (char*)d_ws;
    float* WxT   = (float*)(ws);                                      // 1 MiB
    float* bcat  = (float*)(ws + (1u << 20));                         // 4 KiB
    float* xproj = (float*)(ws + (1u << 20) + (1u << 16));            // 32 MiB
    unsigned short* hB    = (unsigned short*)(ws + (1u << 20) + (1u << 16) + (32u << 20));       // 4 MiB
    unsigned short* WtagB = (unsigned short*)(ws + (1u << 20) + (1u << 16) + (36u << 20));       // 4 MiB

    prep_kernel<<<1024, 256, 0, stream>>>(Wf, Wi, Wg, Wo, bf, bi, bg, bo, WxT, bcat);
    tagprep_kernel<<<2048, 256, 0, stream>>>(Wtag, WtagB);
    xproj_kernel<<<dim3(4, 256), 256, 0, stream>>>(sentence, emb, WxT, bcat, xproj);
    lstm_kernel<<<1, 1024, 0, stream>>>(Wf, Wi, Wg, Wo, xproj, hB);
    logits_kernel<<<dim3(128, 64), 256, 0, stream>>>(hB, WtagB, btag, out);
    lsm_kernel<<<8192, 256, 0, stream>>>(out);
}